// Round 4
// baseline (164.583 us; speedup 1.0000x reference)
//
#include <hip/hip_runtime.h>
#include <math.h>

#define B_ROWS   1024
#define N_SAMP   8192
#define NBINS    140
#define PERIOD   1800   // sin(2*pi*bpm*n/1800) has period 1800 in n for integer bpm
#define KP       2048   // K padded to 64 mfma steps of 32 (zeros in 1800..2047)
#define NCOLP    288    // 280 cols (140 sin | 140 cos) padded to 18 N-tiles of 16
#define NSPLIT   8      // K-split: 8 chunks of 256 k
#define TRIG_BLK (144 * KP / 256)   // 1152 trig blocks appended to prep grid

typedef __attribute__((ext_vector_type(8))) short short8;   // 8 bf16 = 4 VGPRs
typedef __attribute__((ext_vector_type(4))) float f32x4;

__device__ __forceinline__ float wave_reduce_sum(float v) {
    #pragma unroll
    for (int off = 32; off > 0; off >>= 1) v += __shfl_xor(v, off, 64);
    return v;
}

__device__ __forceinline__ unsigned short f2bf(float x) {   // RNE float->bf16
    unsigned int u = __float_as_uint(x);
    unsigned int r = (u + 0x7fff + ((u >> 16) & 1)) >> 16;
    return (unsigned short)r;
}

// ---------------- Kernel 1: fused {trig matrix} + {pearson moments + periodic fold} ----
// Blocks [0,1024): fold row; blocks [1024,1024+1152): fill Tt (independent work, overlaps
// the fold's memory-bound phase). Tt[n][k]: n<140 sin, 140..279 cos, 280..287 zero pad.
__global__ __launch_bounds__(256) void prep(const float* __restrict__ pred,
                                            const float* __restrict__ targ,
                                            unsigned short* __restrict__ gb,
                                            unsigned short* __restrict__ Tt,
                                            float* __restrict__ acc) {
    if (blockIdx.x >= B_ROWS) {
        // ---- trig part: one thread per (n, k) pair, integer-exact phase ----
        int idx = (blockIdx.x - B_ROWS) * 256 + threadIdx.x;   // < 144*2048
        int n = idx >> 11, k = idx & (KP - 1);
        if (n < NBINS) {
            float sv = 0.f, cv = 0.f;
            if (k < PERIOD) {
                int m = ((40 + n) * k) % PERIOD;
                float ang = (6.28318530717958647692f / (float)PERIOD) * (float)m;
                __sincosf(ang, &sv, &cv);
            }
            Tt[(size_t)n * KP + k]           = f2bf(sv);
            Tt[(size_t)(NBINS + n) * KP + k] = f2bf(cv);
        } else {
            int zr = 280 + ((n - NBINS) << 1);
            Tt[(size_t)zr * KP + k]       = 0;
            Tt[(size_t)(zr + 1) * KP + k] = 0;
        }
        return;
    }
    // ---- fold + pearson part ----
    const int row = blockIdx.x;
    const float* p = pred + (size_t)row * N_SAMP;
    const float* t = targ + (size_t)row * N_SAMP;
    float sx[4] = {0,0,0,0}, sy[4] = {0,0,0,0}, sxy[4] = {0,0,0,0};
    float sxx[4] = {0,0,0,0}, syy[4] = {0,0,0,0};
    const float hc = 6.28318530717958647692f / 8191.0f;  // np.hanning(8192)
    #pragma unroll
    for (int pass = 0; pass < 2; ++pass) {
        const int qd = threadIdx.x + 256 * pass;         // 0..511 residue-quads
        float ga[4] = {0,0,0,0};
        if (qd < 450) {
            #pragma unroll
            for (int q = 0; q < 5; ++q) {
                if (q < 4 || qd < 248) {                 // 4*248 + 7200 == 8192 exactly
                    const int n = 4 * qd + PERIOD * q;
                    const float4 pv = *(const float4*)(p + n);
                    const float4 tv = *(const float4*)(t + n);
                    const float pc[4] = {pv.x, pv.y, pv.z, pv.w};
                    const float tc[4] = {tv.x, tv.y, tv.z, tv.w};
                    #pragma unroll
                    for (int i = 0; i < 4; ++i) {
                        sx[i] += pc[i]; sy[i] += tc[i];
                        sxy[i] = fmaf(pc[i], tc[i], sxy[i]);
                        sxx[i] = fmaf(pc[i], pc[i], sxx[i]);
                        syy[i] = fmaf(tc[i], tc[i], syy[i]);
                        float h = 0.5f - 0.5f * __cosf(hc * (float)(n + i));
                        ga[i] = fmaf(pc[i], h, ga[i]);
                    }
                }
            }
        }
        ushort4 o;
        o.x = f2bf(ga[0]); o.y = f2bf(ga[1]); o.z = f2bf(ga[2]); o.w = f2bf(ga[3]);
        *(ushort4*)(gb + (size_t)row * KP + 4 * qd) = o;
    }
    float vals[5];
    vals[0] = sx[0]+sx[1]+sx[2]+sx[3];
    vals[1] = sy[0]+sy[1]+sy[2]+sy[3];
    vals[2] = sxy[0]+sxy[1]+sxy[2]+sxy[3];
    vals[3] = sxx[0]+sxx[1]+sxx[2]+sxx[3];
    vals[4] = syy[0]+syy[1]+syy[2]+syy[3];
    #pragma unroll
    for (int i = 0; i < 5; ++i) vals[i] = wave_reduce_sum(vals[i]);
    __shared__ float red[4][5];
    int wid = threadIdx.x >> 6, lane = threadIdx.x & 63;
    if (lane == 0) {
        #pragma unroll
        for (int i = 0; i < 5; ++i) red[wid][i] = vals[i];
    }
    __syncthreads();
    if (threadIdx.x == 0) {
        float m[5];
        #pragma unroll
        for (int i = 0; i < 5; ++i) m[i] = red[0][i] + red[1][i] + red[2][i] + red[3][i];
        const float N = (float)N_SAMP;
        float num = N * m[2] - m[0] * m[1];
        float den = sqrtf((N * m[3] - m[0] * m[0]) * (N * m[4] - m[1] * m[1]));
        atomicAdd(&acc[0], 1.0f - num / den);
    }
}

// ---------------- Kernel 2: MFMA GEMM  scp[ks] = gb(1024xKP) . Tt^T  -------------------
// grid (64 M-tiles, 8 K-splits) x 256 threads (4 waves). Wave wid: sub=wid&1 owns
// N-tiles [9*sub, 9*sub+9), half=wid>>1 owns K-halves of the 256-k chunk (4 steps each).
// K-halves reduced through LDS -> 2048 waves of parallelism at unchanged scp traffic.
// A/B frags: 16B contiguous loads; C/D: col=lane&15, row=(lane>>4)*4+reg (m89-verified).
__global__ __launch_bounds__(256) void spectrum(const unsigned short* __restrict__ gb,
                                                const unsigned short* __restrict__ Tt,
                                                float* __restrict__ scp) {
    __shared__ float lred[2][9][256];   // 18 KB
    const int lane = threadIdx.x & 63;
    const int wid  = threadIdx.x >> 6;
    const int sub  = wid & 1, half = wid >> 1;
    const int mt   = blockIdx.x;
    const int ks   = blockIdx.y;
    const int t0   = sub * 9;
    const int mrow = mt * 16 + (lane & 15);
    const int kbase = ks * 256 + half * 128 + ((lane >> 4) << 3);
    const short* ga = (const short*)gb + (size_t)mrow * KP + kbase;
    const short* tb = (const short*)Tt + kbase;
    f32x4 acc[9];
    #pragma unroll
    for (int t = 0; t < 9; ++t) acc[t] = (f32x4){0.f, 0.f, 0.f, 0.f};
    #pragma unroll
    for (int s = 0; s < 4; ++s) {
        short8 a = *(const short8*)(ga + s * 32);
        #pragma unroll
        for (int t = 0; t < 9; ++t) {
            const int n = (t0 + t) * 16 + (lane & 15);
            short8 b = *(const short8*)(tb + (size_t)n * KP + s * 32);
            acc[t] = __builtin_amdgcn_mfma_f32_16x16x32_bf16(a, b, acc[t], 0, 0, 0);
        }
    }
    if (half == 1) {
        #pragma unroll
        for (int t = 0; t < 9; ++t)
            #pragma unroll
            for (int i = 0; i < 4; ++i) lred[sub][t][lane * 4 + i] = acc[t][i];
    }
    __syncthreads();
    if (half == 0) {
        float* base = scp + ((size_t)ks * B_ROWS + (size_t)mt * 16) * NCOLP;
        const int col0  = lane & 15;
        const int rbase = (lane >> 4) * 4;
        #pragma unroll
        for (int t = 0; t < 9; ++t)
            #pragma unroll
            for (int i = 0; i < 4; ++i) {
                float v = acc[t][i] + lred[sub][t][lane * 4 + i];
                base[(size_t)(rbase + i) * NCOLP + (t0 + t) * 16 + col0] = v;
            }
    }
}

// ---------------- Kernel 3: reduce splits -> power -> log_softmax -> CE+KL -> finalize --
// Last block to finish (device-scope ticket) applies curriculum alpha/beta and writes out.
__global__ __launch_bounds__(64) void post(const float* __restrict__ scp,
                                           const int* __restrict__ hr,
                                           const int* __restrict__ epoch_p,
                                           float* __restrict__ acc,
                                           float* __restrict__ out) {
    const int b = blockIdx.x;
    const int l = threadIdx.x;
    const int h = hr[b];
    float cav[3]; float casum = 0.f;
    #pragma unroll
    for (int u = 0; u < 3; ++u) {
        int j = l + 64 * u;
        float v = 0.f;
        if (j < NBINS) {
            float s = 0.f, c = 0.f;
            #pragma unroll
            for (int sp = 0; sp < NSPLIT; ++sp) {
                const float* pp = scp + ((size_t)sp * B_ROWS + b) * NCOLP;
                s += pp[j]; c += pp[NBINS + j];
            }
            v = fmaf(s, s, c * c);
        }
        cav[u] = v; casum += v;
    }
    casum = wave_reduce_sum(casum);
    const float inv = 1.0f / casum;
    float x[3]; float m = -1e30f;
    #pragma unroll
    for (int u = 0; u < 3; ++u) {
        int j = l + 64 * u;
        x[u] = cav[u] * inv;
        if (j < NBINS) m = fmaxf(m, x[u]);
    }
    #pragma unroll
    for (int off = 32; off > 0; off >>= 1) m = fmaxf(m, __shfl_xor(m, off, 64));
    float esum = 0.f;
    #pragma unroll
    for (int u = 0; u < 3; ++u) {
        int j = l + 64 * u;
        if (j < NBINS) esum += __expf(x[u] - m);
    }
    esum = wave_reduce_sum(esum);
    const float lse = m + __logf(esum);
    float ce = 0.f, kl = 0.f;
    #pragma unroll
    for (int u = 0; u < 3; ++u) {
        int j = l + 64 * u;
        if (j < NBINS) {
            float logp = x[u] - lse;
            if (j == h) ce = -logp;
            float d = (float)j - (float)h;
            float tt = __expf(-0.5f * d * d) * 0.39894228040143267794f;
            tt = fmaxf(tt, 1e-15f);
            kl += __expf(tt) * (tt - logp);
        }
    }
    ce = wave_reduce_sum(ce);
    kl = wave_reduce_sum(kl) * (1.0f / NBINS);
    if (l == 0) {
        atomicAdd(&acc[1], ce);
        atomicAdd(&acc[2], kl);
        __threadfence();
        unsigned tk = atomicAdd(((unsigned int*)acc) + 3, 1u);
        if (tk == gridDim.x - 1) {            // last block: finalize
            __threadfence();
            float pear = __hip_atomic_load(&acc[0], __ATOMIC_RELAXED, __HIP_MEMORY_SCOPE_AGENT);
            float cet  = __hip_atomic_load(&acc[1], __ATOMIC_RELAXED, __HIP_MEMORY_SCOPE_AGENT);
            float klt  = __hip_atomic_load(&acc[2], __ATOMIC_RELAXED, __HIP_MEMORY_SCOPE_AGENT);
            float temporal = pear * (1.0f / B_ROWS);
            float cem      = cet  * (1.0f / B_ROWS);
            float klm      = klt  * (1.0f / B_ROWS);
            int epoch = epoch_p[0];
            float alpha, beta;
            if (epoch > 25) { alpha = 0.05f; beta = 2.0f; }
            else {
                float e = (float)epoch / 25.0f;
                alpha = 0.1f * exp2f(-e);
                beta  = exp2f(e);
            }
            out[0] = alpha * temporal + beta * (cem + klm);
        }
    }
}

extern "C" void kernel_launch(void* const* d_in, const int* in_sizes, int n_in,
                              void* d_out, int out_size, void* d_ws, size_t ws_size,
                              hipStream_t stream) {
    const int*   epoch = (const int*)d_in[0];
    const float* pred  = (const float*)d_in[1];
    const float* targ  = (const float*)d_in[2];
    const int*   hr    = (const int*)d_in[3];
    float* out = (float*)d_out;

    char* ws = (char*)d_ws;
    float*          acc = (float*)ws;                       // acc[0..2] + ticket
    unsigned short* gb  = (unsigned short*)(ws + 256);      // 1024 x 2048 bf16 (4 MB)
    unsigned short* Tt  = (unsigned short*)(ws + 256 + (size_t)B_ROWS * KP * 2);   // 288 x 2048 bf16
    float*          scp = (float*)(ws + 256 + (size_t)B_ROWS * KP * 2
                                        + (size_t)NCOLP * KP * 2);  // 8 x 1024 x 288 fp32

    hipMemsetAsync(acc, 0, 16, stream);

    prep<<<B_ROWS + TRIG_BLK, 256, 0, stream>>>(pred, targ, gb, Tt, acc);
    spectrum<<<dim3(B_ROWS / 16, NSPLIT), 256, 0, stream>>>(gb, Tt, scp);
    post<<<B_ROWS, 64, 0, stream>>>(scp, hr, epoch, acc, out);
}

// Round 5
// 115.491 us; speedup vs baseline: 1.4251x; 1.4251x over previous
//
#include <hip/hip_runtime.h>
#include <math.h>

#define B_ROWS   1024
#define N_SAMP   8192
#define NBINS    140
#define PERIOD   1800   // sin(2*pi*bpm*n/1800) has period 1800 in n for integer bpm
#define KP       2048   // K padded to 64 mfma steps of 32 (zeros in 1800..2047)
#define NCOLP    288    // 280 cols (140 sin | 140 cos) padded to 18 N-tiles of 16
#define NSPLIT   8      // K-split: 8 chunks of 256 k
#define KSTEPS   8
#define TRIG_BLK (144 * KP / 256)   // 1152 trig blocks appended to prep grid

typedef __attribute__((ext_vector_type(8))) short short8;   // 8 bf16 = 4 VGPRs
typedef __attribute__((ext_vector_type(4))) float f32x4;

__device__ __forceinline__ float wave_reduce_sum(float v) {
    #pragma unroll
    for (int off = 32; off > 0; off >>= 1) v += __shfl_xor(v, off, 64);
    return v;
}

__device__ __forceinline__ unsigned short f2bf(float x) {   // RNE float->bf16
    unsigned int u = __float_as_uint(x);
    unsigned int r = (u + 0x7fff + ((u >> 16) & 1)) >> 16;
    return (unsigned short)r;
}

// ---------------- Kernel 1: fused {trig matrix} + {pearson + periodic fold} ------------
// Blocks [0,1024): fold row, pearson -> plain store pparr[row] (NO atomics).
// Blocks [1024,2176): fill Tt[n][k]: n<140 sin, 140..279 cos, 280..287 zero pad.
__global__ __launch_bounds__(256) void prep(const float* __restrict__ pred,
                                            const float* __restrict__ targ,
                                            unsigned short* __restrict__ gb,
                                            unsigned short* __restrict__ Tt,
                                            float* __restrict__ pparr) {
    if (blockIdx.x >= B_ROWS) {
        int idx = (blockIdx.x - B_ROWS) * 256 + threadIdx.x;   // < 144*2048
        int n = idx >> 11, k = idx & (KP - 1);
        if (n < NBINS) {
            float sv = 0.f, cv = 0.f;
            if (k < PERIOD) {
                int m = ((40 + n) * k) % PERIOD;               // integer-exact phase
                float ang = (6.28318530717958647692f / (float)PERIOD) * (float)m;
                __sincosf(ang, &sv, &cv);
            }
            Tt[(size_t)n * KP + k]           = f2bf(sv);
            Tt[(size_t)(NBINS + n) * KP + k] = f2bf(cv);
        } else {
            int zr = 280 + ((n - NBINS) << 1);
            Tt[(size_t)zr * KP + k]       = 0;
            Tt[(size_t)(zr + 1) * KP + k] = 0;
        }
        return;
    }
    const int row = blockIdx.x;
    const float* p = pred + (size_t)row * N_SAMP;
    const float* t = targ + (size_t)row * N_SAMP;
    float sx[4] = {0,0,0,0}, sy[4] = {0,0,0,0}, sxy[4] = {0,0,0,0};
    float sxx[4] = {0,0,0,0}, syy[4] = {0,0,0,0};
    const float hc = 6.28318530717958647692f / 8191.0f;  // np.hanning(8192)
    #pragma unroll
    for (int pass = 0; pass < 2; ++pass) {
        const int qd = threadIdx.x + 256 * pass;         // 0..511 residue-quads
        float ga[4] = {0,0,0,0};
        if (qd < 450) {
            #pragma unroll
            for (int q = 0; q < 5; ++q) {
                if (q < 4 || qd < 248) {                 // 4*248 + 7200 == 8192 exactly
                    const int n = 4 * qd + PERIOD * q;
                    const float4 pv = *(const float4*)(p + n);
                    const float4 tv = *(const float4*)(t + n);
                    const float pc[4] = {pv.x, pv.y, pv.z, pv.w};
                    const float tc[4] = {tv.x, tv.y, tv.z, tv.w};
                    #pragma unroll
                    for (int i = 0; i < 4; ++i) {
                        sx[i] += pc[i]; sy[i] += tc[i];
                        sxy[i] = fmaf(pc[i], tc[i], sxy[i]);
                        sxx[i] = fmaf(pc[i], pc[i], sxx[i]);
                        syy[i] = fmaf(tc[i], tc[i], syy[i]);
                        float h = 0.5f - 0.5f * __cosf(hc * (float)(n + i));
                        ga[i] = fmaf(pc[i], h, ga[i]);
                    }
                }
            }
        }
        ushort4 o;
        o.x = f2bf(ga[0]); o.y = f2bf(ga[1]); o.z = f2bf(ga[2]); o.w = f2bf(ga[3]);
        *(ushort4*)(gb + (size_t)row * KP + 4 * qd) = o;
    }
    float vals[5];
    vals[0] = sx[0]+sx[1]+sx[2]+sx[3];
    vals[1] = sy[0]+sy[1]+sy[2]+sy[3];
    vals[2] = sxy[0]+sxy[1]+sxy[2]+sxy[3];
    vals[3] = sxx[0]+sxx[1]+sxx[2]+sxx[3];
    vals[4] = syy[0]+syy[1]+syy[2]+syy[3];
    #pragma unroll
    for (int i = 0; i < 5; ++i) vals[i] = wave_reduce_sum(vals[i]);
    __shared__ float red[4][5];
    int wid = threadIdx.x >> 6, lane = threadIdx.x & 63;
    if (lane == 0) {
        #pragma unroll
        for (int i = 0; i < 5; ++i) red[wid][i] = vals[i];
    }
    __syncthreads();
    if (threadIdx.x == 0) {
        float m[5];
        #pragma unroll
        for (int i = 0; i < 5; ++i) m[i] = red[0][i] + red[1][i] + red[2][i] + red[3][i];
        const float N = (float)N_SAMP;
        float num = N * m[2] - m[0] * m[1];
        float den = sqrtf((N * m[3] - m[0] * m[0]) * (N * m[4] - m[1] * m[1]));
        pparr[row] = 1.0f - num / den;                   // plain store, no atomic
    }
}

// ---------------- Kernel 2: MFMA GEMM  scp[ks] = gb(1024xKP) . Tt^T  -------------------
// grid (64 M-tiles, 8 K-splits), block 128 = 2 waves; wave w owns N-tiles [9w, 9w+9).
// A/B frags: 16B contiguous loads; C/D: col=lane&15, row=(lane>>4)*4+reg (m89-verified).
__global__ __launch_bounds__(128) void spectrum(const unsigned short* __restrict__ gb,
                                                const unsigned short* __restrict__ Tt,
                                                float* __restrict__ scp) {
    const int lane = threadIdx.x & 63;
    const int wid  = threadIdx.x >> 6;          // 0..1
    const int mt   = blockIdx.x;
    const int ks   = blockIdx.y;
    const int t0   = wid * 9;
    const int mrow = mt * 16 + (lane & 15);
    const int kbase = ks * (KSTEPS * 32) + ((lane >> 4) << 3);
    const short* ga = (const short*)gb + (size_t)mrow * KP + kbase;
    const short* tb = (const short*)Tt + kbase;
    f32x4 acc[9];
    #pragma unroll
    for (int t = 0; t < 9; ++t) acc[t] = (f32x4){0.f, 0.f, 0.f, 0.f};
    #pragma unroll
    for (int s = 0; s < KSTEPS; ++s) {
        short8 a = *(const short8*)(ga + s * 32);
        #pragma unroll
        for (int t = 0; t < 9; ++t) {
            const int n = (t0 + t) * 16 + (lane & 15);
            short8 b = *(const short8*)(tb + (size_t)n * KP + s * 32);
            acc[t] = __builtin_amdgcn_mfma_f32_16x16x32_bf16(a, b, acc[t], 0, 0, 0);
        }
    }
    float* base = scp + ((size_t)ks * B_ROWS + (size_t)mt * 16) * NCOLP;
    const int col0  = lane & 15;
    const int rbase = (lane >> 4) * 4;
    #pragma unroll
    for (int t = 0; t < 9; ++t)
        #pragma unroll
        for (int i = 0; i < 4; ++i)
            base[(size_t)(rbase + i) * NCOLP + (t0 + t) * 16 + col0] = acc[t][i];
}

// ---------------- Kernel 3: reduce splits -> power -> log_softmax -> CE+KL partial ------
// 256 blocks x 4 waves; wave w owns row b = blockIdx.x*4 + w. Plain store carr[b] (ce+kl).
__global__ __launch_bounds__(256) void post(const float* __restrict__ scp,
                                            const int* __restrict__ hr,
                                            float* __restrict__ carr) {
    const int b = blockIdx.x * 4 + (threadIdx.x >> 6);
    const int l = threadIdx.x & 63;
    const int h = hr[b];
    float cav[3]; float casum = 0.f;
    #pragma unroll
    for (int u = 0; u < 3; ++u) {
        int j = l + 64 * u;
        float v = 0.f;
        if (j < NBINS) {
            float s = 0.f, c = 0.f;
            #pragma unroll
            for (int sp = 0; sp < NSPLIT; ++sp) {
                const float* pp = scp + ((size_t)sp * B_ROWS + b) * NCOLP;
                s += pp[j]; c += pp[NBINS + j];
            }
            v = fmaf(s, s, c * c);
        }
        cav[u] = v; casum += v;
    }
    casum = wave_reduce_sum(casum);
    const float inv = 1.0f / casum;
    float x[3]; float m = -1e30f;
    #pragma unroll
    for (int u = 0; u < 3; ++u) {
        int j = l + 64 * u;
        x[u] = cav[u] * inv;
        if (j < NBINS) m = fmaxf(m, x[u]);
    }
    #pragma unroll
    for (int off = 32; off > 0; off >>= 1) m = fmaxf(m, __shfl_xor(m, off, 64));
    float esum = 0.f;
    #pragma unroll
    for (int u = 0; u < 3; ++u) {
        int j = l + 64 * u;
        if (j < NBINS) esum += __expf(x[u] - m);
    }
    esum = wave_reduce_sum(esum);
    const float lse = m + __logf(esum);
    float ce = 0.f, kl = 0.f;
    #pragma unroll
    for (int u = 0; u < 3; ++u) {
        int j = l + 64 * u;
        if (j < NBINS) {
            float logp = x[u] - lse;
            if (j == h) ce = -logp;
            float d = (float)j - (float)h;
            float tt = __expf(-0.5f * d * d) * 0.39894228040143267794f;
            tt = fmaxf(tt, 1e-15f);
            kl += __expf(tt) * (tt - logp);
        }
    }
    ce = wave_reduce_sum(ce);
    kl = wave_reduce_sum(kl) * (1.0f / NBINS);
    if (l == 0) carr[b] = ce + kl;                       // plain store, no atomic
}

// ---------------- Kernel 4: final reduce (1024 pear + 1024 ce+kl) + curriculum ---------
__global__ __launch_bounds__(256) void finalize(const float* __restrict__ pparr,
                                                const float* __restrict__ carr,
                                                const int* __restrict__ epoch_p,
                                                float* __restrict__ out) {
    const int i = threadIdx.x;
    const float4 pv = *(const float4*)(pparr + 4 * i);
    const float4 cv = *(const float4*)(carr + 4 * i);
    float ps = pv.x + pv.y + pv.z + pv.w;
    float cs = cv.x + cv.y + cv.z + cv.w;
    ps = wave_reduce_sum(ps);
    cs = wave_reduce_sum(cs);
    __shared__ float red[4][2];
    int wid = i >> 6, lane = i & 63;
    if (lane == 0) { red[wid][0] = ps; red[wid][1] = cs; }
    __syncthreads();
    if (i == 0) {
        float pear = red[0][0] + red[1][0] + red[2][0] + red[3][0];
        float cekl = red[0][1] + red[1][1] + red[2][1] + red[3][1];
        float temporal = pear * (1.0f / B_ROWS);
        float cm       = cekl * (1.0f / B_ROWS);
        int epoch = epoch_p[0];
        float alpha, beta;
        if (epoch > 25) { alpha = 0.05f; beta = 2.0f; }
        else {
            float e = (float)epoch / 25.0f;
            alpha = 0.1f * exp2f(-e);
            beta  = exp2f(e);
        }
        out[0] = alpha * temporal + beta * cm;
    }
}

extern "C" void kernel_launch(void* const* d_in, const int* in_sizes, int n_in,
                              void* d_out, int out_size, void* d_ws, size_t ws_size,
                              hipStream_t stream) {
    const int*   epoch = (const int*)d_in[0];
    const float* pred  = (const float*)d_in[1];
    const float* targ  = (const float*)d_in[2];
    const int*   hr    = (const int*)d_in[3];
    float* out = (float*)d_out;

    char* ws = (char*)d_ws;
    float*          pparr = (float*)ws;                         // 1024 f (pearson per row)
    float*          carr  = (float*)(ws + 4096);                // 1024 f (ce+kl per row)
    unsigned short* gb    = (unsigned short*)(ws + 8192);       // 1024 x 2048 bf16 (4 MB)
    unsigned short* Tt    = (unsigned short*)(ws + 8192 + (size_t)B_ROWS * KP * 2);
    float*          scp   = (float*)(ws + 8192 + (size_t)B_ROWS * KP * 2
                                          + (size_t)NCOLP * KP * 2);  // 8 x 1024 x 288 f32

    prep<<<B_ROWS + TRIG_BLK, 256, 0, stream>>>(pred, targ, gb, Tt, pparr);
    spectrum<<<dim3(B_ROWS / 16, NSPLIT), 128, 0, stream>>>(gb, Tt, scp);
    post<<<B_ROWS / 4, 256, 0, stream>>>(scp, hr, carr);
    finalize<<<1, 256, 0, stream>>>(pparr, carr, epoch, out);
}